// Round 1
// baseline (821.101 us; speedup 1.0000x reference)
//
#include <hip/hip_runtime.h>
#include <hip/hip_bf16.h>
#include <math.h>

// GRU decoder: embed+relu -> gi GEMM -> 64-step recurrence (grid-sync) ->
// vocab projection (bf16 MFMA, logits into d_out) -> in-place log_softmax.

typedef __bf16 bf16x8 __attribute__((ext_vector_type(8)));
typedef float  f32x4  __attribute__((ext_vector_type(4)));
typedef unsigned short u16;
typedef u16 u16x8v __attribute__((ext_vector_type(8)));
typedef u16 u16x4v __attribute__((ext_vector_type(4)));

#define BTV (32L * 64 * 32000)

// ---- ws layout (bytes) ----
#define OFF_X    (0L)
#define SZ_X     (2048L * 256 * 2)
#define OFF_WIH  (OFF_X + SZ_X)
#define SZ_WIH   (1536L * 256 * 2)
#define OFF_WHH  (OFF_WIH + SZ_WIH)
#define SZ_WHH   (1536L * 512 * 2)
#define OFF_WOUT (OFF_WHH + SZ_WHH)
#define SZ_WOUT  (32000L * 512 * 2)
#define OFF_GI   (OFF_WOUT + SZ_WOUT)
#define SZ_GI    (2048L * 1536 * 4)
#define OFF_HF   (OFF_GI + SZ_GI)
#define SZ_HF    (2L * 32 * 512 * 4)
#define OFF_HB   (OFF_HF + SZ_HF)
#define SZ_HB    (2L * 32 * 512 * 2)
#define OFF_HS   (OFF_HB + SZ_HB)
#define SZ_HS    (2048L * 512 * 2)
#define OFF_BAR  (OFF_HS + SZ_HS)
#define SZ_BAR   (128L)
#define WS_NEED  (OFF_BAR + SZ_BAR)

__device__ __forceinline__ u16 f2bf(float f) {
  union { float f; unsigned u; } a; a.f = f;
  unsigned r = a.u + 0x7fffu + ((a.u >> 16) & 1u);
  return (u16)(r >> 16);
}

__device__ __forceinline__ void gload16(const void* g, void* l) {
  __builtin_amdgcn_global_load_lds(
      (const __attribute__((address_space(1))) unsigned int*)g,
      (__attribute__((address_space(3))) unsigned int*)l, 16, 0, 0);
}

// ---------------- cast f32 -> bf16 (grid-stride float4) ----------------
extern "C" __global__ void k_cast(const float* __restrict__ s, u16* __restrict__ d, int n4) {
  int i = blockIdx.x * blockDim.x + threadIdx.x;
  int st = gridDim.x * blockDim.x;
  for (; i < n4; i += st) {
    float4 v = reinterpret_cast<const float4*>(s)[i];
    u16x4v o; o.x = f2bf(v.x); o.y = f2bf(v.y); o.z = f2bf(v.z); o.w = f2bf(v.w);
    reinterpret_cast<u16x4v*>(d)[i] = o;
  }
}

// ---------------- embed + relu -> X[t*32+b][256] bf16 ----------------
extern "C" __global__ void k_embed(const float* __restrict__ emb, const int* __restrict__ tgt,
                                   u16* __restrict__ X) {
  int idx = blockIdx.x * 256 + threadIdx.x;  // 65536 total
  int row = idx >> 5;                        // 0..2047  (= t*32 + b)
  int c8  = (idx & 31) << 3;
  int t = row >> 5, b = row & 31;
  int token = (t == 0) ? 0 : tgt[b * 64 + t - 1];
  const float* e = emb + (long)token * 256 + c8;
  u16x8v o;
#pragma unroll
  for (int i = 0; i < 8; ++i) { float v = e[i]; o[i] = f2bf(v > 0.f ? v : 0.f); }
  *reinterpret_cast<u16x8v*>(X + (long)row * 256 + c8) = o;
}

// ---------------- h0 init + barrier zero ----------------
extern "C" __global__ void k_init(const float* __restrict__ eh, float* __restrict__ Hf,
                                  u16* __restrict__ Hb, unsigned* __restrict__ bar) {
  int i = blockIdx.x * 256 + threadIdx.x;  // 16384
  float v = eh[i];
  Hf[i] = v; Hb[i] = f2bf(v);
  if (i < 32) bar[i] = 0u;
}

// ---------------- generic bf16 MFMA GEMM, C = A*B^T + bias ----------------
// A [M][K] bf16, B [N][K] bf16, C [M][N] f32. 128x128 tile, BK=32, 4 waves.
extern "C" __global__ void __launch_bounds__(256)
k_gemm_bt(const u16* __restrict__ A, const u16* __restrict__ B,
          const float* __restrict__ bias, float* __restrict__ C,
          int M, int N, int K) {
  __shared__ u16 At[128 * 32];
  __shared__ u16 Bt[128 * 32];
  int mt = M >> 7;
  int bn = blockIdx.x / mt, bm = blockIdx.x % mt;  // bn-major: B tile shared by run of blocks
  int tid = threadIdx.x, wave = tid >> 6, lane = tid & 63;
  int wr = wave >> 1, wc = wave & 1;
  f32x4 acc[4][4] = {};
  const u16* ga = A + (long)(bm * 128 + wave * 32 + (lane >> 2)) * K + ((lane & 3) << 3);
  const u16* gb = B + (long)(bn * 128 + wave * 32 + (lane >> 2)) * K + ((lane & 3) << 3);
  u16* la0 = &At[wave * 1024]; u16* la1 = la0 + 512;
  u16* lb0 = &Bt[wave * 1024]; u16* lb1 = lb0 + 512;
  long k16 = 16L * K;
  for (int k0 = 0; k0 < K; k0 += 32) {
    if (k0) __syncthreads();
    gload16(ga + k0, la0);
    gload16(ga + k16 + k0, la1);
    gload16(gb + k0, lb0);
    gload16(gb + k16 + k0, lb1);
    __syncthreads();
    bf16x8 af[4], bfr[4];
#pragma unroll
    for (int mi = 0; mi < 4; ++mi)
      af[mi] = *reinterpret_cast<const bf16x8*>(
          &At[(wr * 64 + mi * 16 + (lane & 15)) * 32 + ((lane >> 4) << 3)]);
#pragma unroll
    for (int ni = 0; ni < 4; ++ni)
      bfr[ni] = *reinterpret_cast<const bf16x8*>(
          &Bt[(wc * 64 + ni * 16 + (lane & 15)) * 32 + ((lane >> 4) << 3)]);
#pragma unroll
    for (int mi = 0; mi < 4; ++mi)
#pragma unroll
      for (int ni = 0; ni < 4; ++ni)
        acc[mi][ni] = __builtin_amdgcn_mfma_f32_16x16x32_bf16(af[mi], bfr[ni], acc[mi][ni], 0, 0, 0);
  }
  int rb = bm * 128 + wr * 64 + ((lane >> 4) << 2);
  int cb = bn * 128 + wc * 64 + (lane & 15);
#pragma unroll
  for (int mi = 0; mi < 4; ++mi)
#pragma unroll
    for (int ni = 0; ni < 4; ++ni) {
      int col = cb + ni * 16;
      float bv = bias[col];
#pragma unroll
      for (int q = 0; q < 4; ++q) {
        int rr = rb + mi * 16 + q;
        C[(long)rr * N + col] = acc[mi][ni][q] + bv;
      }
    }
}

// ---------------- GRU recurrence: 32 blocks x 128 thr, grid barrier ----------------
extern "C" __global__ void __launch_bounds__(128)
k_gru(const float* __restrict__ gi, const u16* __restrict__ Whh,
      const float* __restrict__ bhh,
      float* __restrict__ Hf, u16* __restrict__ Hb,
      u16* __restrict__ HS, float* __restrict__ outH,
      unsigned* __restrict__ bar) {
  __shared__ float gh[3][32][16];
  int g = blockIdx.x, j0 = g * 16;
  int tid = threadIdx.x, wave = tid >> 6, lane = tid & 63;
  const u16* w0 = Whh + (long)(j0 + (lane & 15)) * 512 + ((lane >> 4) << 3);
  const u16* w1 = Whh + (long)(512 + j0 + (lane & 15)) * 512 + ((lane >> 4) << 3);
  const u16* w2 = Whh + (long)(1024 + j0 + (lane & 15)) * 512 + ((lane >> 4) << 3);
  unsigned phase = 0;
  for (int t = 0; t < 64; ++t) {
    int cur = t & 1, nxt = cur ^ 1;
    const u16* hc = Hb + cur * 16384 + (wave * 16 + (lane & 15)) * 512 + ((lane >> 4) << 3);
    f32x4 a0 = {}, a1 = {}, a2 = {};
#pragma unroll
    for (int kt = 0; kt < 16; ++kt) {
      bf16x8 av = *reinterpret_cast<const bf16x8*>(hc + kt * 32);
      a0 = __builtin_amdgcn_mfma_f32_16x16x32_bf16(av, *reinterpret_cast<const bf16x8*>(w0 + kt * 32), a0, 0, 0, 0);
      a1 = __builtin_amdgcn_mfma_f32_16x16x32_bf16(av, *reinterpret_cast<const bf16x8*>(w1 + kt * 32), a1, 0, 0, 0);
      a2 = __builtin_amdgcn_mfma_f32_16x16x32_bf16(av, *reinterpret_cast<const bf16x8*>(w2 + kt * 32), a2, 0, 0, 0);
    }
    int br = wave * 16 + ((lane >> 4) << 2);
    int cl = lane & 15;
#pragma unroll
    for (int q = 0; q < 4; ++q) {
      gh[0][br + q][cl] = a0[q];
      gh[1][br + q][cl] = a1[q];
      gh[2][br + q][cl] = a2[q];
    }
    __syncthreads();
    const float* gib = gi + (long)t * 32 * 1536;
    for (int o = tid; o < 512; o += 128) {
      int b = o >> 4, jl = o & 15, j = j0 + jl;
      float ir = gib[b * 1536 + j];
      float iz = gib[b * 1536 + 512 + j];
      float inn = gib[b * 1536 + 1024 + j];
      float hr = gh[0][b][jl] + bhh[j];
      float hz = gh[1][b][jl] + bhh[512 + j];
      float hn = gh[2][b][jl] + bhh[1024 + j];
      float r = 1.f / (1.f + __expf(-(ir + hr)));
      float z = 1.f / (1.f + __expf(-(iz + hz)));
      float x = inn + r * hn;
      float ax = fabsf(x), ee = __expf(-2.f * ax);
      float th = (1.f - ee) / (1.f + ee);
      th = x < 0.f ? -th : th;
      float hp = Hf[cur * 16384 + b * 512 + j];
      float hnew = (1.f - z) * th + z * hp;
      Hf[nxt * 16384 + b * 512 + j] = hnew;
      Hb[nxt * 16384 + b * 512 + j] = f2bf(hnew);
      HS[((long)b * 64 + t) * 512 + j] = f2bf(hnew);  // row = b*64 + t for projection
      if (t == 63) outH[b * 512 + j] = hnew;
    }
    __syncthreads();
    if (tid == 0) {
      __threadfence();
      ++phase;
      if (atomicAdd(&bar[0], 1u) == 31u) {
        atomicExch(&bar[0], 0u);
        __threadfence();
        atomicExch(&bar[1], phase);
      } else {
        while (atomicAdd(&bar[1], 0u) < phase) { }
      }
      __threadfence();
    }
    __syncthreads();
  }
}

// ---------------- in-place log_softmax over rows of 32000 ----------------
extern "C" __global__ void __launch_bounds__(512)
k_lsm(float* __restrict__ P) {
  extern __shared__ float sr[];
  __shared__ float red[8];
  long base = (long)blockIdx.x * 32000;
  int tid = threadIdx.x, wave = tid >> 6, lane = tid & 63;
  float mx = -INFINITY;
  for (int i = tid; i < 8000; i += 512) {
    float4 v = reinterpret_cast<const float4*>(P + base)[i];
    reinterpret_cast<float4*>(sr)[i] = v;
    mx = fmaxf(mx, fmaxf(fmaxf(v.x, v.y), fmaxf(v.z, v.w)));
  }
#pragma unroll
  for (int off = 32; off; off >>= 1) mx = fmaxf(mx, __shfl_down(mx, off, 64));
  if (lane == 0) red[wave] = mx;
  __syncthreads();
  if (tid == 0) {
    float m = red[0];
#pragma unroll
    for (int w = 1; w < 8; ++w) m = fmaxf(m, red[w]);
    red[0] = m;
  }
  __syncthreads();
  mx = red[0];
  __syncthreads();
  float sm = 0.f;
  for (int i = tid; i < 8000; i += 512) {
    float4 v = reinterpret_cast<const float4*>(sr)[i];
    sm += __expf(v.x - mx) + __expf(v.y - mx) + __expf(v.z - mx) + __expf(v.w - mx);
  }
#pragma unroll
  for (int off = 32; off; off >>= 1) sm += __shfl_down(sm, off, 64);
  if (lane == 0) red[wave] = sm;
  __syncthreads();
  if (tid == 0) {
    float s = 0.f;
#pragma unroll
    for (int w = 0; w < 8; ++w) s += red[w];
    red[0] = mx + __logf(s);
  }
  __syncthreads();
  float L = red[0];
  for (int i = tid; i < 8000; i += 512) {
    float4 v = reinterpret_cast<const float4*>(sr)[i];
    v.x -= L; v.y -= L; v.z -= L; v.w -= L;
    reinterpret_cast<float4*>(P + base)[i] = v;
  }
}

extern "C" void kernel_launch(void* const* d_in, const int* in_sizes, int n_in,
                              void* d_out, int out_size, void* d_ws, size_t ws_size,
                              hipStream_t stream) {
  (void)in_sizes; (void)n_in; (void)out_size;
  const float* enc_hid = (const float*)d_in[1];
  const int*   tgt     = (const int*)d_in[2];
  const float* emb     = (const float*)d_in[3];
  const float* W_ih    = (const float*)d_in[4];
  const float* W_hh    = (const float*)d_in[5];
  const float* b_ih    = (const float*)d_in[6];
  const float* b_hh    = (const float*)d_in[7];
  const float* W_out   = (const float*)d_in[8];
  const float* b_out   = (const float*)d_in[9];
  float* out = (float*)d_out;
  char* ws = (char*)d_ws;
  if (ws_size < (size_t)WS_NEED) return;

  u16* X    = (u16*)(ws + OFF_X);
  u16* Wih  = (u16*)(ws + OFF_WIH);
  u16* Whh  = (u16*)(ws + OFF_WHH);
  u16* Wout = (u16*)(ws + OFF_WOUT);
  float* gi = (float*)(ws + OFF_GI);
  float* Hf = (float*)(ws + OFF_HF);
  u16* Hb   = (u16*)(ws + OFF_HB);
  u16* HS   = (u16*)(ws + OFF_HS);
  unsigned* bar = (unsigned*)(ws + OFF_BAR);

  hipFuncSetAttribute(reinterpret_cast<const void*>(k_lsm),
                      hipFuncAttributeMaxDynamicSharedMemorySize, 131072);

  k_cast<<<96, 256, 0, stream>>>(W_ih, Wih, 1536 * 256 / 4);
  k_cast<<<192, 256, 0, stream>>>(W_hh, Whh, 1536 * 512 / 4);
  k_cast<<<2048, 256, 0, stream>>>(W_out, Wout, 32000 * 512 / 4);
  k_embed<<<256, 256, 0, stream>>>(emb, tgt, X);
  k_init<<<64, 256, 0, stream>>>(enc_hid, Hf, Hb, bar);
  k_gemm_bt<<<(1536 / 128) * (2048 / 128), 256, 0, stream>>>(X, Wih, b_ih, gi, 2048, 1536, 256);
  k_gru<<<32, 128, 0, stream>>>(gi, Whh, b_hh, Hf, Hb, HS, out + BTV, bar);
  k_gemm_bt<<<(32000 / 128) * (2048 / 128), 256, 0, stream>>>(HS, Wout, b_out, out, 2048, 32000, 512);
  k_lsm<<<2048, 512, 128000, stream>>>(out);
}